// Round 1
// baseline (187.374 us; speedup 1.0000x reference)
//
#include <hip/hip_runtime.h>
#include <hip/hip_fp16.h>
#include <stdint.h>

// ---------------------------------------------------------------------------
// CIN block: 3 layers of out[b,k,d] = relu(sum_ij h[b,i,d] feat[b,j,d] W[k,i,j] + b[k])
// B=512, D=32, F0=32, K=256 per layer, SPLIT_HALF -> h = out[:, :128].
// GEMM view: m=(b,d), Out[m,k] = sum_i ( diag(h[:,i]) * F ) @ W[:,i,:]^T
// A-frag built in-register: F-frag (resident) * per-lane scalar h[m,i].
// ---------------------------------------------------------------------------

typedef _Float16 half8_t __attribute__((ext_vector_type(8)));
typedef float f32x4 __attribute__((ext_vector_type(4)));
typedef uint32_t u32x4 __attribute__((ext_vector_type(4)));

union H8 {
  half8_t h;
  uint32_t u[4];
  u32x4 q;
};

#define AS1 __attribute__((address_space(1)))
#define AS3 __attribute__((address_space(3)))

// ---- prep: W [k][i][j] f32 -> Wt [i][k][j] f16 -------------------------------
__global__ void conv_w_kernel(const float* __restrict__ W, uint16_t* __restrict__ Wt,
                              int FLsh, int n2) {
  int idx2 = blockIdx.x * 256 + threadIdx.x;
  if (idx2 >= n2) return;
  float2 xy = *(const float2*)(W + (size_t)idx2 * 2);
  int j2 = idx2 & 15;
  int i = (idx2 >> 4) & ((1 << FLsh) - 1);
  int k = idx2 >> (4 + FLsh);
  __half2 h2 = __floats2half2_rn(xy.x, xy.y);
  *(uint32_t*)(Wt + ((size_t)(i * 256 + k) * 32 + j2 * 2)) = *(uint32_t*)&h2;
}

// ---- prep: feat [b][j][d] f32 -> F16 [m][j] f16  and Fdup [j][m] u32(dup f16)
__global__ void conv_feat_kernel(const float* __restrict__ feat,
                                 uint16_t* __restrict__ F16,
                                 uint32_t* __restrict__ Fdup) {
  int m = blockIdx.x * 256 + threadIdx.x;  // 0..16383
  int b = m >> 5, d = m & 31;
  const float* fb = feat + (size_t)b * 1024 + d;
  uint16_t hs[32];
#pragma unroll
  for (int j = 0; j < 32; ++j) {
    float x = fb[j * 32];
    uint16_t u = __half_as_ushort(__float2half(x));
    hs[j] = u;
    Fdup[(size_t)j * 16384 + m] = (uint32_t)u * 0x10001u;
  }
#pragma unroll
  for (int c = 0; c < 4; ++c) {
    u32x4 q;
    q[0] = (uint32_t)hs[c * 8 + 0] | ((uint32_t)hs[c * 8 + 1] << 16);
    q[1] = (uint32_t)hs[c * 8 + 2] | ((uint32_t)hs[c * 8 + 3] << 16);
    q[2] = (uint32_t)hs[c * 8 + 4] | ((uint32_t)hs[c * 8 + 5] << 16);
    q[3] = (uint32_t)hs[c * 8 + 6] | ((uint32_t)hs[c * 8 + 7] << 16);
    *(u32x4*)(F16 + (size_t)m * 32 + c * 8) = q;
  }
}

// ---- stage one i-slice of Wt ([256][32] f16 = 16KB) into LDS, swizzled ------
// LDS layout: 16B chunk c -> (k = c>>2, slot = c&3); slot holds j-group
// g = slot ^ ((k>>1)&3)  => frag reads are 2-way bank aliased (free).
__device__ __forceinline__ void stage_b(const uint16_t* wti, char* lds_base, int tid) {
#pragma unroll
  for (int r = 0; r < 2; ++r) {
    int c = tid + r * 512;
    int src = (c & ~3) | ((c & 3) ^ ((c >> 3) & 3));
    __builtin_amdgcn_global_load_lds((const AS1 uint32_t*)(wti + src * 8),
                                     (AS3 uint32_t*)(lds_base + c * 16), 16, 0, 0);
  }
}

// ---- fused CIN layer GEMM ---------------------------------------------------
// grid 256 (m-tiles of 64), block 512 (8 waves, 1x8 over N=256; wave tile 64x32)
__global__ __launch_bounds__(512) void gemm_cin(
    const uint32_t* __restrict__ hdup,   // [FL][16384] dup-f16 pairs
    const uint16_t* __restrict__ wt,     // [FL][256][32] f16
    const uint16_t* __restrict__ f16m,   // [16384][32] f16
    const float* __restrict__ bias,      // [256]
    uint32_t* __restrict__ hout,         // [128][16384] dup-f16, or null
    float* __restrict__ outp,            // [512][512] f32
    int FL, int obase, int klo) {
  __shared__ __align__(16) char smem[65536];  // [0,32K): B dbuf; [32K,64K): h
  const int HB = 32768;
  int tid = threadIdx.x;
  int lane = tid & 63, w = tid >> 6;
  int m0 = blockIdx.x * 64;

  // stage h tile [FL][64] u32 (dup-f16)
  for (int c = tid; c < FL * 16; c += 512) {
    int i = c >> 4, col = (c & 15) * 4;
    u32x4 q = *(const u32x4*)(hdup + (size_t)i * 16384 + m0 + col);
    *(u32x4*)(smem + HB + c * 16) = q;
  }
  // resident F fragments (A-side), row = lane&15, j = (lane>>4)*8 + t
  H8 ff[4];
#pragma unroll
  for (int mf = 0; mf < 4; ++mf) {
    int mrow = m0 + mf * 16 + (lane & 15);
    ff[mf].q = *(const u32x4*)(f16m + (size_t)mrow * 32 + (lane >> 4) * 8);
  }
  // per-lane B-frag byte offsets (swizzled)
  int kb[2];
#pragma unroll
  for (int kf = 0; kf < 2; ++kf) {
    int k = w * 32 + kf * 16 + (lane & 15);
    kb[kf] = k * 64 + ((((lane >> 4) & 3) ^ ((k >> 1) & 3)) << 4);
  }

  f32x4 acc[4][2];
#pragma unroll
  for (int mf = 0; mf < 4; ++mf)
#pragma unroll
    for (int kf = 0; kf < 2; ++kf) acc[mf][kf] = (f32x4)0.f;

  stage_b(wt, smem, tid);  // i = 0 into buf 0
  __syncthreads();

  for (int i = 0; i < FL; ++i) {
    int cur = (i & 1) * 16384;
    if (i + 1 < FL) stage_b(wt + (size_t)(i + 1) * 8192, smem + (16384 - cur), tid);

    H8 bf[2];
#pragma unroll
    for (int kf = 0; kf < 2; ++kf)
      bf[kf].q = *(const u32x4*)(smem + cur + kb[kf]);

#pragma unroll
    for (int mf = 0; mf < 4; ++mf) {
      uint32_t hd = *(const uint32_t*)(smem + HB + (i * 64 + mf * 16 + (lane & 15)) * 4);
      H8 hv;
      hv.u[0] = hd; hv.u[1] = hd; hv.u[2] = hd; hv.u[3] = hd;
      H8 a;
      a.h = ff[mf].h * hv.h;  // 4x v_pk_mul_f16: diag(h)*F
#pragma unroll
      for (int kf = 0; kf < 2; ++kf)
        acc[mf][kf] = __builtin_amdgcn_mfma_f32_16x16x32_f16(a.h, bf[kf].h, acc[mf][kf], 0, 0, 0);
    }
    __syncthreads();
  }

  // ---- epilogue: bias + relu -------------------------------------------------
  float bv[2];
#pragma unroll
  for (int kf = 0; kf < 2; ++kf) bv[kf] = bias[w * 32 + kf * 16 + (lane & 15)];
  float v[4][2][4];
#pragma unroll
  for (int mf = 0; mf < 4; ++mf)
#pragma unroll
    for (int kf = 0; kf < 2; ++kf)
#pragma unroll
      for (int r = 0; r < 4; ++r) {
        float x = acc[mf][kf][r] + bv[kf];
        v[mf][kf][r] = x > 0.f ? x : 0.f;
      }

  // ---- d-reduction -> output (each (b,kcol) owned by exactly one wave) -------
  int b0 = blockIdx.x * 2;
#pragma unroll
  for (int kf = 0; kf < 2; ++kf) {
    float s0 = 0.f, s1 = 0.f;
#pragma unroll
    for (int r = 0; r < 4; ++r) {
      s0 += v[0][kf][r] + v[1][kf][r];
      s1 += v[2][kf][r] + v[3][kf][r];
    }
    s0 += __shfl_xor(s0, 16); s0 += __shfl_xor(s0, 32);
    s1 += __shfl_xor(s1, 16); s1 += __shfl_xor(s1, 32);
    int kcol = w * 32 + kf * 16 + lane;  // valid when lane<16
    if (lane < 16 && kcol >= klo) {
      outp[(size_t)b0 * 512 + obase + kcol - klo] = s0;
      outp[(size_t)(b0 + 1) * 512 + obase + kcol - klo] = s1;
    }
  }

  // ---- h for next layer: LDS transpose -> coalesced dup-f16 rows -------------
  if (hout) {
    if (w < 4) {  // kcol < 128
#pragma unroll
      for (int mf = 0; mf < 4; ++mf)
#pragma unroll
        for (int kf = 0; kf < 2; ++kf)
#pragma unroll
          for (int r = 0; r < 4; ++r) {
            int kcol = w * 32 + kf * 16 + (lane & 15);
            int mloc = mf * 16 + ((lane >> 4) << 2) + r;
            uint32_t du = (uint32_t)__half_as_ushort(__float2half(v[mf][kf][r])) * 0x10001u;
            *(uint32_t*)(smem + (kcol * 68 + mloc) * 4) = du;
          }
    }
    __syncthreads();
    int row = tid >> 2, seg = tid & 3;  // 128 rows x 4 segs of 16 u32
    uint32_t* dst = hout + (size_t)row * 16384 + m0 + seg * 16;
    const char* srcp = smem + (row * 68 + seg * 16) * 4;
#pragma unroll
    for (int c = 0; c < 4; ++c)
      *(u32x4*)(dst + c * 4) = *(const u32x4*)(srcp + c * 16);
  }
}

// ---------------------------------------------------------------------------
extern "C" void kernel_launch(void* const* d_in, const int* in_sizes, int n_in,
                              void* d_out, int out_size, void* d_ws, size_t ws_size,
                              hipStream_t stream) {
  const float* feat = (const float*)d_in[0];
  const float* W0 = (const float*)d_in[1];
  const float* b0 = (const float*)d_in[2];
  const float* W1 = (const float*)d_in[3];
  const float* b1 = (const float*)d_in[4];
  const float* W2 = (const float*)d_in[5];
  const float* b2 = (const float*)d_in[6];
  float* out = (float*)d_out;
  char* ws = (char*)d_ws;

  // workspace layout (bytes)
  uint16_t* Wt0 = (uint16_t*)(ws + 0x000000);         // 32*256*32*2   = 512KB
  uint16_t* Wt1 = (uint16_t*)(ws + 0x080000);         // 128*256*32*2  = 2MB
  uint16_t* Wt2 = (uint16_t*)(ws + 0x280000);         // 2MB
  uint16_t* F16 = (uint16_t*)(ws + 0x480000);         // 16384*32*2    = 1MB
  uint32_t* Fdup = (uint32_t*)(ws + 0x580000);        // 32*16384*4    = 2MB
  uint32_t* h1 = (uint32_t*)(ws + 0x780000);          // 128*16384*4   = 8MB
  uint32_t* h2 = (uint32_t*)(ws + 0xF80000);          // 8MB  (end 24.5MB)

  // prep
  {
    int n2 = 256 * 32 * 16;
    conv_w_kernel<<<(n2 + 255) / 256, 256, 0, stream>>>(W0, Wt0, 5, n2);
  }
  {
    int n2 = 256 * 128 * 16;
    conv_w_kernel<<<(n2 + 255) / 256, 256, 0, stream>>>(W1, Wt1, 7, n2);
    conv_w_kernel<<<(n2 + 255) / 256, 256, 0, stream>>>(W2, Wt2, 7, n2);
  }
  conv_feat_kernel<<<64, 256, 0, stream>>>(feat, F16, Fdup);

  // layers: out cols [0,128)=L0 k>=128, [128,256)=L1 k>=128, [256,512)=L2 all k
  gemm_cin<<<256, 512, 0, stream>>>(Fdup, Wt0, F16, b0, h1, out, 32, 0, 128);
  gemm_cin<<<256, 512, 0, stream>>>(h1, Wt1, F16, b1, h2, out, 128, 128, 128);
  gemm_cin<<<256, 512, 0, stream>>>(h2, Wt2, F16, b2, (uint32_t*)nullptr, out, 128, 256, 0);
}

// Round 2
// 158.764 us; speedup vs baseline: 1.1802x; 1.1802x over previous
//
#include <hip/hip_runtime.h>
#include <hip/hip_fp16.h>
#include <stdint.h>

// ---------------------------------------------------------------------------
// CIN block: 3 layers of out[b,k,d] = relu(sum_ij h[b,i,d] feat[b,j,d] W[k,i,j] + b[k])
// B=512, D=32, F0=32, K=256 per layer, SPLIT_HALF -> h = out[:, :128].
// GEMM view: m=(b,d), Out[m,k] = sum_i ( diag(h[:,i]) * F ) @ W[:,i,:]^T
// A-frag built in-register: F-frag (resident) * per-lane scalar h[m,i].
// R1: barrier-free main loop. B-frags read straight from L2 (chunk-reordered
// W layout -> contiguous 1KB per wave-frag), 2-deep register prefetch.
// ---------------------------------------------------------------------------

typedef _Float16 half8_t __attribute__((ext_vector_type(8)));
typedef float f32x4 __attribute__((ext_vector_type(4)));
typedef uint32_t u32x4 __attribute__((ext_vector_type(4)));

union H8 {
  half8_t h;
  uint32_t u[4];
  u32x4 q;
};

// ---- prep: W [k][i][j] f32 -> Wt chunks: [i][kt][lane][8 f16] ---------------
// lane = g*16 + kr (g = j>>3, kr = k&15, kt = k>>4): wave frag read for
// (w,kf) is the contiguous 1KB at ((i*16 + w*2+kf)*64)*16 bytes, lane-indexed.
__global__ void conv_w_kernel(const float* __restrict__ W, uint16_t* __restrict__ Wt,
                              int FLsh, int n2) {
  int idx2 = blockIdx.x * 256 + threadIdx.x;
  if (idx2 >= n2) return;
  float2 xy = *(const float2*)(W + (size_t)idx2 * 2);
  int j2 = idx2 & 15;
  int i = (idx2 >> 4) & ((1 << FLsh) - 1);
  int k = idx2 >> (4 + FLsh);
  __half2 h2 = __floats2half2_rn(xy.x, xy.y);
  int g = j2 >> 2, kr = k & 15, kt = k >> 4;
  uint32_t* wt32 = (uint32_t*)Wt;
  wt32[(((size_t)i * 16 + kt) * 64 + g * 16 + kr) * 4 + (j2 & 3)] = *(uint32_t*)&h2;
}

// ---- prep: feat [b][j][d] f32 -> F16 [m][j] f16  and Fdup [j][m] u32(dup f16)
__global__ void conv_feat_kernel(const float* __restrict__ feat,
                                 uint16_t* __restrict__ F16,
                                 uint32_t* __restrict__ Fdup) {
  int m = blockIdx.x * 256 + threadIdx.x;  // 0..16383
  int b = m >> 5, d = m & 31;
  const float* fb = feat + (size_t)b * 1024 + d;
  uint16_t hs[32];
#pragma unroll
  for (int j = 0; j < 32; ++j) {
    float x = fb[j * 32];
    uint16_t u = __half_as_ushort(__float2half(x));
    hs[j] = u;
    Fdup[(size_t)j * 16384 + m] = (uint32_t)u * 0x10001u;
  }
#pragma unroll
  for (int c = 0; c < 4; ++c) {
    u32x4 q;
    q[0] = (uint32_t)hs[c * 8 + 0] | ((uint32_t)hs[c * 8 + 1] << 16);
    q[1] = (uint32_t)hs[c * 8 + 2] | ((uint32_t)hs[c * 8 + 3] << 16);
    q[2] = (uint32_t)hs[c * 8 + 4] | ((uint32_t)hs[c * 8 + 5] << 16);
    q[3] = (uint32_t)hs[c * 8 + 6] | ((uint32_t)hs[c * 8 + 7] << 16);
    *(u32x4*)(F16 + (size_t)m * 32 + c * 8) = q;
  }
}

// ---- fused CIN layer GEMM ---------------------------------------------------
// grid 256 (m-tiles of 64), block 512 (8 waves, 1x8 over N=256; wave tile 64x32)
__global__ __launch_bounds__(512) void gemm_cin(
    const uint32_t* __restrict__ hdup,   // [FL][16384] dup-f16 pairs
    const uint16_t* __restrict__ wt,     // [FL][16][64][8] f16 chunks
    const uint16_t* __restrict__ f16m,   // [16384][32] f16
    const float* __restrict__ bias,      // [256]
    uint32_t* __restrict__ hout,         // [128][16384] dup-f16, or null
    float* __restrict__ outp,            // [512][512] f32
    int FL, int obase, int klo) {
  __shared__ __align__(16) char smem[34816];  // h [FL][64]u32 (<=32K); epilogue reuse
  int tid = threadIdx.x;
  int lane = tid & 63, w = tid >> 6;
  int m0 = blockIdx.x * 64;

  // stage h tile [FL][64] u32 (dup-f16) once
  for (int c = tid; c < FL * 16; c += 512) {
    int i = c >> 4, col = (c & 15) * 4;
    u32x4 q = *(const u32x4*)(hdup + (size_t)i * 16384 + m0 + col);
    *(u32x4*)(smem + c * 16) = q;
  }
  // resident F fragments (A-side), row = lane&15, j = (lane>>4)*8 + t
  H8 ff[4];
#pragma unroll
  for (int mf = 0; mf < 4; ++mf) {
    int mrow = m0 + mf * 16 + (lane & 15);
    ff[mf].q = *(const u32x4*)(f16m + (size_t)mrow * 32 + (lane >> 4) * 8);
  }
  // per-lane B-frag global byte offsets within an i-slice (16KB each)
  const char* wp = (const char*)wt;
  int gb0 = ((w * 2 + 0) * 64 + lane) * 16;
  int gb1 = ((w * 2 + 1) * 64 + lane) * 16;

  f32x4 acc[4][2];
#pragma unroll
  for (int mf = 0; mf < 4; ++mf)
#pragma unroll
    for (int kf = 0; kf < 2; ++kf) acc[mf][kf] = (f32x4)0.f;

  // 2-deep B prefetch pipeline (no barriers in main loop)
  H8 b0a, b1a, b0b, b1b;
  b0a.q = *(const u32x4*)(wp + gb0);
  b1a.q = *(const u32x4*)(wp + gb1);
  {
    int i1 = FL > 1 ? 1 : 0;
    b0b.q = *(const u32x4*)(wp + (size_t)i1 * 16384 + gb0);
    b1b.q = *(const u32x4*)(wp + (size_t)i1 * 16384 + gb1);
  }
  __syncthreads();  // h staged

#pragma unroll 2
  for (int i = 0; i < FL; ++i) {
    int ip = (i + 2 < FL) ? i + 2 : FL - 1;
    H8 n0, n1;
    n0.q = *(const u32x4*)(wp + (size_t)ip * 16384 + gb0);
    n1.q = *(const u32x4*)(wp + (size_t)ip * 16384 + gb1);

    uint32_t hd[4];
#pragma unroll
    for (int mf = 0; mf < 4; ++mf)
      hd[mf] = *(const uint32_t*)(smem + (i * 64 + mf * 16 + (lane & 15)) * 4);

#pragma unroll
    for (int mf = 0; mf < 4; ++mf) {
      H8 hv;
      hv.u[0] = hd[mf]; hv.u[1] = hd[mf]; hv.u[2] = hd[mf]; hv.u[3] = hd[mf];
      H8 a;
      a.h = ff[mf].h * hv.h;  // 4x v_pk_mul_f16: diag(h)*F
      acc[mf][0] = __builtin_amdgcn_mfma_f32_16x16x32_f16(a.h, b0a.h, acc[mf][0], 0, 0, 0);
      acc[mf][1] = __builtin_amdgcn_mfma_f32_16x16x32_f16(a.h, b1a.h, acc[mf][1], 0, 0, 0);
    }
    b0a = b0b; b1a = b1b;
    b0b = n0;  b1b = n1;
  }

  // ---- epilogue: bias + relu -------------------------------------------------
  float bv[2];
#pragma unroll
  for (int kf = 0; kf < 2; ++kf) bv[kf] = bias[w * 32 + kf * 16 + (lane & 15)];
  float v[4][2][4];
#pragma unroll
  for (int mf = 0; mf < 4; ++mf)
#pragma unroll
    for (int kf = 0; kf < 2; ++kf)
#pragma unroll
      for (int r = 0; r < 4; ++r) {
        float x = acc[mf][kf][r] + bv[kf];
        v[mf][kf][r] = x > 0.f ? x : 0.f;
      }

  // ---- d-reduction -> output (each (b,kcol) owned by exactly one wave) -------
  int b0 = blockIdx.x * 2;
#pragma unroll
  for (int kf = 0; kf < 2; ++kf) {
    float s0 = 0.f, s1 = 0.f;
#pragma unroll
    for (int r = 0; r < 4; ++r) {
      s0 += v[0][kf][r] + v[1][kf][r];
      s1 += v[2][kf][r] + v[3][kf][r];
    }
    s0 += __shfl_xor(s0, 16); s0 += __shfl_xor(s0, 32);
    s1 += __shfl_xor(s1, 16); s1 += __shfl_xor(s1, 32);
    int kcol = w * 32 + kf * 16 + lane;  // valid when lane<16
    if (lane < 16 && kcol >= klo) {
      outp[(size_t)b0 * 512 + obase + kcol - klo] = s0;
      outp[(size_t)(b0 + 1) * 512 + obase + kcol - klo] = s1;
    }
  }

  // ---- h for next layer: LDS transpose -> coalesced dup-f16 rows -------------
  if (hout) {
    __syncthreads();  // waves drift now: h region still read until all finish loop
    if (w < 4) {  // kcol < 128
#pragma unroll
      for (int mf = 0; mf < 4; ++mf)
#pragma unroll
        for (int kf = 0; kf < 2; ++kf)
#pragma unroll
          for (int r = 0; r < 4; ++r) {
            int kcol = w * 32 + kf * 16 + (lane & 15);
            int mloc = mf * 16 + ((lane >> 4) << 2) + r;
            uint32_t du = (uint32_t)__half_as_ushort(__float2half(v[mf][kf][r])) * 0x10001u;
            *(uint32_t*)(smem + (kcol * 68 + mloc) * 4) = du;
          }
    }
    __syncthreads();
    int row = tid >> 2, seg = tid & 3;  // 128 rows x 4 segs of 16 u32
    uint32_t* dst = hout + (size_t)row * 16384 + m0 + seg * 16;
    const char* srcp = smem + (row * 68 + seg * 16) * 4;
#pragma unroll
    for (int c = 0; c < 4; ++c)
      *(u32x4*)(dst + c * 4) = *(const u32x4*)(srcp + c * 16);
  }
}

// ---------------------------------------------------------------------------
extern "C" void kernel_launch(void* const* d_in, const int* in_sizes, int n_in,
                              void* d_out, int out_size, void* d_ws, size_t ws_size,
                              hipStream_t stream) {
  const float* feat = (const float*)d_in[0];
  const float* W0 = (const float*)d_in[1];
  const float* b0 = (const float*)d_in[2];
  const float* W1 = (const float*)d_in[3];
  const float* b1 = (const float*)d_in[4];
  const float* W2 = (const float*)d_in[5];
  const float* b2 = (const float*)d_in[6];
  float* out = (float*)d_out;
  char* ws = (char*)d_ws;

  // workspace layout (bytes)
  uint16_t* Wt0 = (uint16_t*)(ws + 0x000000);         // 32*256*32*2   = 512KB
  uint16_t* Wt1 = (uint16_t*)(ws + 0x080000);         // 128*256*32*2  = 2MB
  uint16_t* Wt2 = (uint16_t*)(ws + 0x280000);         // 2MB
  uint16_t* F16 = (uint16_t*)(ws + 0x480000);         // 16384*32*2    = 1MB
  uint32_t* Fdup = (uint32_t*)(ws + 0x580000);        // 32*16384*4    = 2MB
  uint32_t* h1 = (uint32_t*)(ws + 0x780000);          // 128*16384*4   = 8MB
  uint32_t* h2 = (uint32_t*)(ws + 0xF80000);          // 8MB  (end 24.5MB)

  // prep
  {
    int n2 = 256 * 32 * 16;
    conv_w_kernel<<<(n2 + 255) / 256, 256, 0, stream>>>(W0, Wt0, 5, n2);
  }
  {
    int n2 = 256 * 128 * 16;
    conv_w_kernel<<<(n2 + 255) / 256, 256, 0, stream>>>(W1, Wt1, 7, n2);
    conv_w_kernel<<<(n2 + 255) / 256, 256, 0, stream>>>(W2, Wt2, 7, n2);
  }
  conv_feat_kernel<<<64, 256, 0, stream>>>(feat, F16, Fdup);

  // layers: out cols [0,128)=L0 k>=128, [128,256)=L1 k>=128, [256,512)=L2 all k
  gemm_cin<<<256, 512, 0, stream>>>(Fdup, Wt0, F16, b0, h1, out, 32, 0, 128);
  gemm_cin<<<256, 512, 0, stream>>>(h1, Wt1, F16, b1, h2, out, 128, 128, 128);
  gemm_cin<<<256, 512, 0, stream>>>(h2, Wt2, F16, b2, (uint32_t*)nullptr, out, 128, 256, 0);
}

// Round 3
// 123.025 us; speedup vs baseline: 1.5231x; 1.2905x over previous
//
#include <hip/hip_runtime.h>
#include <hip/hip_fp16.h>
#include <stdint.h>

// ---------------------------------------------------------------------------
// CIN block: 3 layers of out[b,k,d] = relu(sum_ij h[b,i,d] feat[b,j,d] W[k,i,j] + b[k])
// B=512, D=32, F0=32, K=256 per layer, SPLIT_HALF -> h = out[:, :128].
// GEMM view: m=(b,d), Out[m,k] = sum_i ( diag(h[:,i]) * F ) @ W[:,i,:]^T
// A-frag built in-register: F-frag (resident) * per-lane scalar h[m,i].
// R2: grid 512 (m-tile x k-half, 2 blocks/CU), per-block i-loop phase rotation
// (decorrelate L2 reads across CUs), 4-deep B register prefetch, h via
// transposed LDS layout + ds_read_b128 prefetched one group ahead, fused prep.
// ---------------------------------------------------------------------------

typedef _Float16 half8_t __attribute__((ext_vector_type(8)));
typedef float f32x4 __attribute__((ext_vector_type(4)));
typedef uint32_t u32x4 __attribute__((ext_vector_type(4)));

union H8 {
  half8_t h;
  uint32_t u[4];
  u32x4 q;
};

// ---- fused prep -------------------------------------------------------------
// blocks [0,512): W0   [k][i][j] f32 -> Wt0 chunks [i][kt][g*16+kr][8 f16]
// blocks [512,2560): W1 -> Wt1 ; [2560,4608): W2 -> Wt2
// blocks [4608,4672): feat -> F16 [m][j] f16  and  Fdup [j][m] u32(dup f16)
__global__ void prep_kernel(const float* __restrict__ W0, const float* __restrict__ W1,
                            const float* __restrict__ W2, const float* __restrict__ feat,
                            uint16_t* __restrict__ Wt0, uint16_t* __restrict__ Wt1,
                            uint16_t* __restrict__ Wt2,
                            uint16_t* __restrict__ F16, uint32_t* __restrict__ Fdup) {
  int blk = blockIdx.x;
  if (blk < 4608) {
    const float* W; uint16_t* Wt; int FLsh, base;
    if (blk < 512)       { W = W0; Wt = Wt0; FLsh = 5; base = 0; }
    else if (blk < 2560) { W = W1; Wt = Wt1; FLsh = 7; base = 512; }
    else                 { W = W2; Wt = Wt2; FLsh = 7; base = 2560; }
    int idx2 = (blk - base) * 256 + threadIdx.x;
    float2 xy = *(const float2*)(W + (size_t)idx2 * 2);
    int j2 = idx2 & 15;                       // f16-pair index along j
    int i = (idx2 >> 4) & ((1 << FLsh) - 1);
    int k = idx2 >> (4 + FLsh);
    __half2 h2 = __floats2half2_rn(xy.x, xy.y);
    int g = j2 >> 2, kr = k & 15, kt = k >> 4;
    uint32_t* wt32 = (uint32_t*)Wt;
    wt32[(((size_t)i * 16 + kt) * 64 + g * 16 + kr) * 4 + (j2 & 3)] = *(uint32_t*)&h2;
  } else {
    int m = (blk - 4608) * 256 + threadIdx.x;  // 0..16383
    int b = m >> 5, d = m & 31;
    const float* fb = feat + (size_t)b * 1024 + d;
    uint16_t hs[32];
#pragma unroll
    for (int j = 0; j < 32; ++j) {
      float x = fb[j * 32];
      uint16_t u = __half_as_ushort(__float2half(x));
      hs[j] = u;
      Fdup[(size_t)j * 16384 + m] = (uint32_t)u * 0x10001u;
    }
#pragma unroll
    for (int c = 0; c < 4; ++c) {
      u32x4 q;
      q[0] = (uint32_t)hs[c * 8 + 0] | ((uint32_t)hs[c * 8 + 1] << 16);
      q[1] = (uint32_t)hs[c * 8 + 2] | ((uint32_t)hs[c * 8 + 3] << 16);
      q[2] = (uint32_t)hs[c * 8 + 4] | ((uint32_t)hs[c * 8 + 5] << 16);
      q[3] = (uint32_t)hs[c * 8 + 6] | ((uint32_t)hs[c * 8 + 7] << 16);
      *(u32x4*)(F16 + (size_t)m * 32 + c * 8) = q;
    }
  }
}

// ---- fused CIN layer GEMM ---------------------------------------------------
// grid 512: bx = mt*2 + kh. Block: 8 waves, 64 m-rows, 128 k-cols (kh half).
// Wave w: cols kh*128 + w*16 .. +15, one B-frag/step, 4 MFMA/step.
__global__ __launch_bounds__(512, 4) void gemm_cin(
    const uint32_t* __restrict__ hdup,   // [FL][16384] dup-f16 pairs
    const uint16_t* __restrict__ wt,     // [FL][16][64][8] f16 chunks
    const uint16_t* __restrict__ f16m,   // [16384][32] f16
    const float* __restrict__ bias,      // [256]
    uint32_t* __restrict__ hout,         // [128][16384] dup-f16, or null
    float* __restrict__ outp,            // [512][512] f32
    int FL, int obase, int klo) {
  __shared__ __align__(16) char smem[34816];  // h [FL][16][4]u32; epilogue reuse
  int tid = threadIdx.x;
  int lane = tid & 63, w = tid >> 6;
  int lr = lane & 15;
  int bx = blockIdx.x;
  int mt = bx >> 1, kh = bx & 1;
  int m0 = mt * 64;
  int FLm = FL - 1;
  int i0 = ((bx >> 3) * FL >> 6) & FLm;  // per-block stream phase

  // stage h tile, transposed: hl[(i*16 + lr)*4 + mf] = hdup[i][m0 + mf*16 + lr]
  uint32_t* hl = (uint32_t*)smem;
  for (int c = tid; c < FL * 16; c += 512) {
    int i = c >> 4, seg = (c & 15) * 4;
    u32x4 q = *(const u32x4*)(hdup + (size_t)i * 16384 + m0 + seg);
    int mf = seg >> 4, lrb = seg & 15;
#pragma unroll
    for (int r = 0; r < 4; ++r) hl[(i * 16 + lrb + r) * 4 + mf] = q[r];
  }

  // resident F fragments (A-side), row = lane&15, j = (lane>>4)*8 + t
  H8 ff[4];
#pragma unroll
  for (int mf = 0; mf < 4; ++mf) {
    int mrow = m0 + mf * 16 + lr;
    ff[mf].q = *(const u32x4*)(f16m + (size_t)mrow * 32 + (lane >> 4) * 8);
  }

  // B: per-lane byte offset within a 16KB i-slice; this wave's kt = kh*8+w
  const char* wp = (const char*)wt;
  int gb = ((kh * 8 + w) * 64 + lane) * 16;

  // 4-deep B prefetch ring (distance 4 steps)
  H8 bq[4];
#pragma unroll
  for (int r = 0; r < 4; ++r) {
    int ph = (i0 + r) & FLm;
    bq[r].q = *(const u32x4*)(wp + (size_t)ph * 16384 + gb);
  }

  f32x4 acc[4];
#pragma unroll
  for (int mf = 0; mf < 4; ++mf) acc[mf] = (f32x4)0.f;

  __syncthreads();  // h staged

  // h group 0 (one ds_read_b128 per step)
  H8 hqA[4], hqB[4];
#pragma unroll
  for (int r = 0; r < 4; ++r) {
    int ph = (i0 + r) & FLm;
    hqA[r].q = *(const u32x4*)(smem + (ph * 16 + lr) * 16);
  }

  for (int t = 0; t < FL; t += 4) {
    // issue next h group (wrapped; harmless reload on final group)
#pragma unroll
    for (int r = 0; r < 4; ++r) {
      int ph = (i0 + t + 4 + r) & FLm;
      hqB[r].q = *(const u32x4*)(smem + (ph * 16 + lr) * 16);
    }
#pragma unroll
    for (int r = 0; r < 4; ++r) {
      int ph = (i0 + t + 4 + r) & FLm;
      H8 nb;
      nb.q = *(const u32x4*)(wp + (size_t)ph * 16384 + gb);
#pragma unroll
      for (int mf = 0; mf < 4; ++mf) {
        uint32_t hd = hqA[r].u[mf];
        H8 hv;
        hv.u[0] = hd; hv.u[1] = hd; hv.u[2] = hd; hv.u[3] = hd;
        H8 a;
        a.h = ff[mf].h * hv.h;  // 4x v_pk_mul_f16: diag(h)*F
        acc[mf] = __builtin_amdgcn_mfma_f32_16x16x32_f16(a.h, bq[r].h, acc[mf], 0, 0, 0);
      }
      bq[r] = nb;
    }
#pragma unroll
    for (int r = 0; r < 4; ++r) hqA[r] = hqB[r];
  }

  // ---- epilogue: bias + relu -------------------------------------------------
  int kcol = kh * 128 + w * 16 + lr;
  float bv = bias[kcol];
  float v[4][4];
#pragma unroll
  for (int mf = 0; mf < 4; ++mf)
#pragma unroll
    for (int r = 0; r < 4; ++r) {
      float x = acc[mf][r] + bv;
      v[mf][r] = x > 0.f ? x : 0.f;
    }

  // ---- d-reduction -> output (each (b,kcol) owned by exactly one wave) -------
  int b0 = mt * 2;
  {
    float s0 = 0.f, s1 = 0.f;
#pragma unroll
    for (int r = 0; r < 4; ++r) {
      s0 += v[0][r] + v[1][r];
      s1 += v[2][r] + v[3][r];
    }
    s0 += __shfl_xor(s0, 16); s0 += __shfl_xor(s0, 32);
    s1 += __shfl_xor(s1, 16); s1 += __shfl_xor(s1, 32);
    int kc = kh * 128 + w * 16 + lane;  // valid when lane<16
    if (lane < 16 && kc >= klo) {
      outp[(size_t)b0 * 512 + obase + kc - klo] = s0;
      outp[(size_t)(b0 + 1) * 512 + obase + kc - klo] = s1;
    }
  }

  // ---- h for next layer (kh==0 blocks): LDS transpose -> coalesced rows ------
  if (hout && kh == 0) {
    __syncthreads();  // h region read until all waves finish main loop
#pragma unroll
    for (int mf = 0; mf < 4; ++mf)
#pragma unroll
      for (int r = 0; r < 4; ++r) {
        int mloc = mf * 16 + ((lane >> 4) << 2) + r;
        uint32_t du = (uint32_t)__half_as_ushort(__float2half(v[mf][r])) * 0x10001u;
        *(uint32_t*)(smem + (kcol * 68 + mloc) * 4) = du;
      }
    __syncthreads();
    int row = tid >> 2, seg = tid & 3;  // 128 rows x 4 segs of 16 u32
    uint32_t* dst = hout + (size_t)row * 16384 + m0 + seg * 16;
    const char* srcp = smem + (row * 68 + seg * 16) * 4;
#pragma unroll
    for (int c = 0; c < 4; ++c)
      *(u32x4*)(dst + c * 4) = *(const u32x4*)(srcp + c * 16);
  }
}

// ---------------------------------------------------------------------------
extern "C" void kernel_launch(void* const* d_in, const int* in_sizes, int n_in,
                              void* d_out, int out_size, void* d_ws, size_t ws_size,
                              hipStream_t stream) {
  const float* feat = (const float*)d_in[0];
  const float* W0 = (const float*)d_in[1];
  const float* b0 = (const float*)d_in[2];
  const float* W1 = (const float*)d_in[3];
  const float* b1 = (const float*)d_in[4];
  const float* W2 = (const float*)d_in[5];
  const float* b2 = (const float*)d_in[6];
  float* out = (float*)d_out;
  char* ws = (char*)d_ws;

  // workspace layout (bytes)
  uint16_t* Wt0 = (uint16_t*)(ws + 0x000000);         // 32*256*32*2   = 512KB
  uint16_t* Wt1 = (uint16_t*)(ws + 0x080000);         // 128*256*32*2  = 2MB
  uint16_t* Wt2 = (uint16_t*)(ws + 0x280000);         // 2MB
  uint16_t* F16 = (uint16_t*)(ws + 0x480000);         // 16384*32*2    = 1MB
  uint32_t* Fdup = (uint32_t*)(ws + 0x580000);        // 32*16384*4    = 2MB
  uint32_t* h1 = (uint32_t*)(ws + 0x780000);          // 128*16384*4   = 8MB
  uint32_t* h2 = (uint32_t*)(ws + 0xF80000);          // 8MB  (end 24.5MB)

  prep_kernel<<<4672, 256, 0, stream>>>(W0, W1, W2, feat, Wt0, Wt1, Wt2, F16, Fdup);

  // layers: out cols [0,128)=L0 k>=128, [128,256)=L1 k>=128, [256,512)=L2 all k
  gemm_cin<<<512, 512, 0, stream>>>(Fdup, Wt0, F16, b0, h1, out, 32, 0, 128);
  gemm_cin<<<512, 512, 0, stream>>>(h1, Wt1, F16, b1, h2, out, 128, 128, 128);
  gemm_cin<<<512, 512, 0, stream>>>(h2, Wt2, F16, b2, (uint32_t*)nullptr, out, 128, 256, 0);
}

// Round 4
// 106.669 us; speedup vs baseline: 1.7566x; 1.1533x over previous
//
#include <hip/hip_runtime.h>
#include <hip/hip_fp16.h>
#include <stdint.h>

// ---------------------------------------------------------------------------
// CIN block: 3 layers of out[b,k,d] = relu(sum_ij h[b,i,d] feat[b,j,d] W[k,i,j] + b[k])
// GEMM view: m=(b,d), Out[m,k] = sum_i ( diag(h[:,i]) * F ) @ W[:,i,:]^T
// R3: BM=128 x k-half blocks (grid 256, 1024 thr, 16 waves = 4/SIMD).
// W staged via global_load_lds into 4-buf LDS ring, counted vmcnt(2) + raw
// s_barrier (no drain). Swapped MFMA operands (A=W, B=diag(h)F) so C has m
// along lanes -> coalesced direct global h-panel write, shfl d-reduction.
// h as packed f16 pairs in 32KB LDS; A-build = v_perm dup + v_pk_mul_f16.
// ---------------------------------------------------------------------------

typedef _Float16 half8_t __attribute__((ext_vector_type(8)));
typedef float f32x4 __attribute__((ext_vector_type(4)));
typedef uint32_t u32x4 __attribute__((ext_vector_type(4)));

union H8 {
  half8_t h;
  uint32_t u[4];
  u32x4 q;
};

#define AS1 __attribute__((address_space(1)))
#define AS3 __attribute__((address_space(3)))

static __device__ __forceinline__ uint32_t pkmul(uint32_t x, uint32_t y) {
  __half2 a = __builtin_bit_cast(__half2, x);
  __half2 b = __builtin_bit_cast(__half2, y);
  __half2 r = __hmul2(a, b);
  return __builtin_bit_cast(uint32_t, r);
}

// ---- fused prep -------------------------------------------------------------
// blocks [0,512): W0 [k][i][j] f32 -> Wt0 chunks [i][kt][g*16+kr][8 f16]
// blocks [512,2560): W1 ; [2560,4608): W2 ; [4608,4672): feat -> F16 + Fpack
__global__ void prep_kernel(const float* __restrict__ W0, const float* __restrict__ W1,
                            const float* __restrict__ W2, const float* __restrict__ feat,
                            uint16_t* __restrict__ Wt0, uint16_t* __restrict__ Wt1,
                            uint16_t* __restrict__ Wt2,
                            uint16_t* __restrict__ F16, uint16_t* __restrict__ Fpack) {
  int blk = blockIdx.x;
  if (blk < 4608) {
    const float* W; uint16_t* Wt; int FLsh, base;
    if (blk < 512)       { W = W0; Wt = Wt0; FLsh = 5; base = 0; }
    else if (blk < 2560) { W = W1; Wt = Wt1; FLsh = 7; base = 512; }
    else                 { W = W2; Wt = Wt2; FLsh = 7; base = 2560; }
    int idx2 = (blk - base) * 256 + threadIdx.x;
    float2 xy = *(const float2*)(W + (size_t)idx2 * 2);
    int j2 = idx2 & 15;                       // f16-pair index along j
    int i = (idx2 >> 4) & ((1 << FLsh) - 1);
    int k = idx2 >> (4 + FLsh);
    __half2 h2 = __floats2half2_rn(xy.x, xy.y);
    int g = j2 >> 2, kr = k & 15, kt = k >> 4;
    uint32_t* wt32 = (uint32_t*)Wt;
    wt32[(((size_t)i * 16 + kt) * 64 + g * 16 + kr) * 4 + (j2 & 3)] = *(uint32_t*)&h2;
  } else {
    int m = (blk - 4608) * 256 + threadIdx.x;  // 0..16383
    int b = m >> 5, d = m & 31;
    const float* fb = feat + (size_t)b * 1024 + d;
    uint16_t hs[32];
#pragma unroll
    for (int j = 0; j < 32; ++j)
      hs[j] = __half_as_ushort(__float2half(fb[j * 32]));
    // Fpack: [j][8192 pairs][2] u16; pair p = (m>>5)*16 + (m&15), half=(m>>4)&1
    int pidx = (m >> 5) * 16 + (m & 15);
    int hf = (m >> 4) & 1;
#pragma unroll
    for (int j = 0; j < 32; ++j)
      Fpack[((size_t)j * 8192 + pidx) * 2 + hf] = hs[j];
#pragma unroll
    for (int c = 0; c < 4; ++c) {
      u32x4 q;
      q[0] = (uint32_t)hs[c * 8 + 0] | ((uint32_t)hs[c * 8 + 1] << 16);
      q[1] = (uint32_t)hs[c * 8 + 2] | ((uint32_t)hs[c * 8 + 3] << 16);
      q[2] = (uint32_t)hs[c * 8 + 4] | ((uint32_t)hs[c * 8 + 5] << 16);
      q[3] = (uint32_t)hs[c * 8 + 6] | ((uint32_t)hs[c * 8 + 7] << 16);
      *(u32x4*)(F16 + (size_t)m * 32 + c * 8) = q;
    }
  }
}

// ---- fused CIN layer GEMM ---------------------------------------------------
// grid 256: bx = mt*2 + kh. Block 1024 thr (16 waves = 4 mw x 4 kw),
// tile 128m x 128k; wave tile 32m x 32k (mf=2 via B-op, kf=2 via A-op).
__global__ __launch_bounds__(1024) void gemm_cin(
    const uint32_t* __restrict__ hsrc,  // packed f16-pair source
    int hblock, int hstride,            // u32 offsets: per-mt, per-i
    const uint16_t* __restrict__ wt,    // [FL][16 kt][64][8] f16 chunks
    const uint16_t* __restrict__ f16m,  // [16384][32] f16
    const float* __restrict__ bias,     // [256]
    uint32_t* __restrict__ hout,        // panel [mt][128 k][64] u32 pairs, or null
    float* __restrict__ outp,           // [512][512] f32
    int FL, int obase, int klo) {
  __shared__ __align__(16) char smem[65536];  // [0,32K) W ring x4; [32K,64K) h
  char* hlds = smem + 32768;
  const int tid = threadIdx.x;
  const int lane = tid & 63, w = tid >> 6;
  const int lr = lane & 15, hi = lane >> 4;
  const int bx = blockIdx.x;
  const int mt = bx >> 1, kh = bx & 1;
  const int m0 = mt * 128;
  const int FLm = FL - 1;
  const int phase = (bx * 37) & FLm;
  const int mw = w >> 2, kw = w & 3;
  const bool stager = (w < 8);

  // --- prologue: stage h (packed pairs) into LDS, linear ---
  const uint32_t* hb = hsrc + (size_t)mt * hblock;
  for (int qq = tid; qq < FL * 16; qq += 1024) {
    int i = qq >> 4, q4 = qq & 15;
    __builtin_amdgcn_global_load_lds(
        (const AS1 uint32_t*)(hb + (size_t)i * hstride + q4 * 4),
        (AS3 uint32_t*)(hlds + qq * 16), 16, 0, 0);
  }
  // --- resident F fragments (B-op): col m = lane&15, j = hi*8+e ---
  H8 ff0, ff1;
  ff0.q = *(const u32x4*)(f16m + ((size_t)m0 + mw * 32 + lr) * 32 + hi * 8);
  ff1.q = *(const u32x4*)(f16m + ((size_t)m0 + mw * 32 + 16 + lr) * 32 + hi * 8);

  const char* wbase = (const char*)wt + kh * 8192;
  if (stager) {
#pragma unroll
    for (int r = 0; r < 3; ++r) {
      int sl = (r + phase) & FLm;
      __builtin_amdgcn_global_load_lds(
          (const AS1 uint32_t*)(wbase + (size_t)sl * 16384 + w * 1024 + lane * 16),
          (AS3 uint32_t*)(smem + r * 8192 + w * 1024 + lane * 16), 16, 0, 0);
    }
  } else {
    asm volatile("s_waitcnt vmcnt(0)" ::: "memory");  // drain own h stages
  }

  f32x4 acc00 = {0.f, 0.f, 0.f, 0.f}, acc01 = acc00, acc10 = acc00, acc11 = acc00;

  for (int t = 0; t < FL; ++t) {
    const int sl = (t + phase) & FLm;
    if (stager) { asm volatile("s_waitcnt vmcnt(2)" ::: "memory"); }
    asm volatile("s_barrier" ::: "memory");
    const char* buf = smem + (t & 3) * 8192;
    H8 wf0, wf1;
    wf0.q = *(const u32x4*)(buf + (kw * 2 + 0) * 1024 + lane * 16);
    wf1.q = *(const u32x4*)(buf + (kw * 2 + 1) * 1024 + lane * 16);
    uint32_t hp = *(const uint32_t*)(hlds + (sl * 64 + mw * 16 + lr) * 4);
    if (stager) {
      int sl3 = (t + 3 + phase) & FLm;
      __builtin_amdgcn_global_load_lds(
          (const AS1 uint32_t*)(wbase + (size_t)sl3 * 16384 + w * 1024 + lane * 16),
          (AS3 uint32_t*)(smem + ((t + 3) & 3) * 8192 + w * 1024 + lane * 16), 16, 0, 0);
    }
    // dup halves of hp: e0 = (lo,lo), e1 = (hi,hi) via v_perm
    uint32_t e0 = __builtin_amdgcn_perm(hp, hp, 0x01000100u);
    uint32_t e1 = __builtin_amdgcn_perm(hp, hp, 0x03020302u);
    H8 a0, a1;
#pragma unroll
    for (int c = 0; c < 4; ++c) {
      a0.u[c] = pkmul(ff0.u[c], e0);
      a1.u[c] = pkmul(ff1.u[c], e1);
    }
    acc00 = __builtin_amdgcn_mfma_f32_16x16x32_f16(wf0.h, a0.h, acc00, 0, 0, 0);
    acc01 = __builtin_amdgcn_mfma_f32_16x16x32_f16(wf0.h, a1.h, acc01, 0, 0, 0);
    acc10 = __builtin_amdgcn_mfma_f32_16x16x32_f16(wf1.h, a0.h, acc10, 0, 0, 0);
    acc11 = __builtin_amdgcn_mfma_f32_16x16x32_f16(wf1.h, a1.h, acc11, 0, 0, 0);
  }

  // ---- epilogue: bias + relu (C: row = k_sub = hi*4+r, col = m_sub = lr) ----
  float bv[2][4];
#pragma unroll
  for (int kf = 0; kf < 2; ++kf)
#pragma unroll
    for (int r = 0; r < 4; ++r)
      bv[kf][r] = bias[kh * 128 + kw * 32 + kf * 16 + hi * 4 + r];
  float v[2][2][4];  // [kf][mf][r]
#pragma unroll
  for (int r = 0; r < 4; ++r) {
    float x;
    x = acc00[r] + bv[0][r]; v[0][0][r] = x > 0.f ? x : 0.f;
    x = acc01[r] + bv[0][r]; v[0][1][r] = x > 0.f ? x : 0.f;
    x = acc10[r] + bv[1][r]; v[1][0][r] = x > 0.f ? x : 0.f;
    x = acc11[r] + bv[1][r]; v[1][1][r] = x > 0.f ? x : 0.f;
  }

  // ---- h panel for next layer: direct coalesced global write ----------------
  if (hout != nullptr && kh == 0) {
#pragma unroll
    for (int kf = 0; kf < 2; ++kf)
#pragma unroll
      for (int r = 0; r < 4; ++r) {
        int k_loc = kw * 32 + kf * 16 + hi * 4 + r;
        uint32_t lo = __half_as_ushort(__float2half(v[kf][0][r]));
        uint32_t hi16 = __half_as_ushort(__float2half(v[kf][1][r]));
        hout[(size_t)mt * 8192 + k_loc * 64 + mw * 16 + lr] = lo | (hi16 << 16);
      }
  }

  // ---- d-reduction (sum over mf regs + lr lanes) -> output -------------------
  int b = mt * 4 + mw;
#pragma unroll
  for (int kf = 0; kf < 2; ++kf) {
    float s[4];
#pragma unroll
    for (int r = 0; r < 4; ++r) {
      float x = v[kf][0][r] + v[kf][1][r];
      x += __shfl_xor(x, 1);
      x += __shfl_xor(x, 2);
      x += __shfl_xor(x, 4);
      x += __shfl_xor(x, 8);
      s[r] = x;
    }
    if (lr == 0) {
      int kbase = kh * 128 + kw * 32 + kf * 16 + hi * 4;
#pragma unroll
      for (int r = 0; r < 4; ++r) {
        int k = kbase + r;
        if (k >= klo) outp[(size_t)b * 512 + obase + k - klo] = s[r];
      }
    }
  }
  // drain pending LDS-DMA before endpgm (LDS may be reallocated)
  asm volatile("s_waitcnt vmcnt(0)" ::: "memory");
}

// ---------------------------------------------------------------------------
extern "C" void kernel_launch(void* const* d_in, const int* in_sizes, int n_in,
                              void* d_out, int out_size, void* d_ws, size_t ws_size,
                              hipStream_t stream) {
  const float* feat = (const float*)d_in[0];
  const float* W0 = (const float*)d_in[1];
  const float* b0 = (const float*)d_in[2];
  const float* W1 = (const float*)d_in[3];
  const float* b1 = (const float*)d_in[4];
  const float* W2 = (const float*)d_in[5];
  const float* b2 = (const float*)d_in[6];
  float* out = (float*)d_out;
  char* ws = (char*)d_ws;

  // workspace layout (bytes)
  uint16_t* Wt0  = (uint16_t*)(ws + 0x000000);  // 512KB
  uint16_t* Wt1  = (uint16_t*)(ws + 0x080000);  // 2MB
  uint16_t* Wt2  = (uint16_t*)(ws + 0x280000);  // 2MB
  uint16_t* F16  = (uint16_t*)(ws + 0x480000);  // 1MB
  uint16_t* Fpk  = (uint16_t*)(ws + 0x580000);  // 1MB   [j][8192] u32 pairs
  uint32_t* h1   = (uint32_t*)(ws + 0x680000);  // 4MB   [mt][128][64] u32
  uint32_t* h2   = (uint32_t*)(ws + 0xA80000);  // 4MB   (end 14.5MB)

  prep_kernel<<<4672, 256, 0, stream>>>(W0, W1, W2, feat, Wt0, Wt1, Wt2, F16, Fpk);

  // layers: out cols [0,128)=L0 k>=128, [128,256)=L1 k>=128, [256,512)=L2 all k
  gemm_cin<<<256, 1024, 0, stream>>>((const uint32_t*)Fpk, 64, 8192, Wt0, F16, b0,
                                     h1, out, 32, 0, 128);
  gemm_cin<<<256, 1024, 0, stream>>>(h1, 8192, 64, Wt1, F16, b1,
                                     h2, out, 128, 128, 128);
  gemm_cin<<<256, 1024, 0, stream>>>(h2, 8192, 64, Wt2, F16, b2,
                                     (uint32_t*)nullptr, out, 128, 256, 0);
}